// Round 5
// baseline (635.116 us; speedup 1.0000x reference)
//
#include <hip/hip_runtime.h>

#define TOK 4096
#define NE 16
#define HD 2048
#define ID 1024
#define QGROUP 16
#define CAP 4096

typedef _Float16 half4v __attribute__((ext_vector_type(4)));
typedef _Float16 half8v __attribute__((ext_vector_type(8)));
typedef float float4v __attribute__((ext_vector_type(4)));

// ---------------- prep: x fp32 -> f16 ----------------
__global__ __launch_bounds__(256) void prep_kernel(
    const float* __restrict__ x, _Float16* __restrict__ xh)
{
    int i8 = (blockIdx.x * 256 + threadIdx.x) * 8;
    float4 f0 = *(const float4*)&x[i8];
    float4 f1 = *(const float4*)&x[i8 + 4];
    half8v h;
    h[0] = (_Float16)f0.x; h[1] = (_Float16)f0.y; h[2] = (_Float16)f0.z; h[3] = (_Float16)f0.w;
    h[4] = (_Float16)f1.x; h[5] = (_Float16)f1.y; h[6] = (_Float16)f1.z; h[7] = (_Float16)f1.w;
    *(half8v*)&xh[i8] = h;
}

// ---------------- router ----------------
__global__ __launch_bounds__(256) void router_kernel(
    const float* __restrict__ x, const float* __restrict__ gw,
    int* __restrict__ counts, int* __restrict__ pair_row, float* __restrict__ pair_w)
{
    int t = blockIdx.x;
    int tid = threadIdx.x;
    float p[NE];
#pragma unroll
    for (int e = 0; e < NE; e++) p[e] = 0.f;
    const float* xr = x + (size_t)t * HD;
    for (int h = tid; h < HD; h += 256) {
        float xv = xr[h];
#pragma unroll
        for (int e = 0; e < NE; e++) p[e] = fmaf(xv, gw[e * HD + h], p[e]);
    }
#pragma unroll
    for (int off = 32; off > 0; off >>= 1) {
#pragma unroll
        for (int e = 0; e < NE; e++) p[e] += __shfl_down(p[e], off, 64);
    }
    __shared__ float part[4][NE];
    int wave = tid >> 6, lane = tid & 63;
    if (lane == 0) {
#pragma unroll
        for (int e = 0; e < NE; e++) part[wave][e] = p[e];
    }
    __syncthreads();
    if (tid == 0) {
        float s[NE]; float sum = 0.f;
#pragma unroll
        for (int e = 0; e < NE; e++) {
            float l = part[0][e] + part[1][e] + part[2][e] + part[3][e];
            float sg = 1.f / (1.f + expf(-l));
            s[e] = sg; sum += sg;
        }
        int i1 = 0;
#pragma unroll
        for (int e = 1; e < NE; e++) if (s[e] > s[i1]) i1 = e;
        int i2 = (i1 == 0) ? 1 : 0;
#pragma unroll
        for (int e = 0; e < NE; e++) if (e != i1 && s[e] > s[i2]) i2 = e;
        float p1 = s[i1] / sum, p2 = s[i2] / sum;
        float inv = 1.f / (p1 + p2 + 1e-20f);
        float w1 = p1 * inv, w2 = p2 * inv;
        int s1 = atomicAdd(&counts[i1], 1);
        pair_row[i1 * CAP + s1] = t * 2;     pair_w[i1 * CAP + s1] = w1;
        int s2 = atomicAdd(&counts[i2], 1);
        pair_row[i2 * CAP + s2] = t * 2 + 1; pair_w[i2 * CAP + s2] = w2;
    }
}

// ---------------- grouped MFMA GEMM, register-prefetch pipelined ----------------
// Tile: 64M x 128N x BK=64. 4 waves as 2x2, each wave 32Mx64N (2x4 frags of 16x16x32 f16).
template<int N, int K, bool UP>
__global__ __launch_bounds__(256) void gemm_kernel(
    const _Float16* __restrict__ A, const int* __restrict__ qw,
    const float* __restrict__ bsc, const float* __restrict__ gsc,
    const int* __restrict__ counts, const int* __restrict__ pair_row,
    const float* __restrict__ pair_w,
    _Float16* __restrict__ store16, float* __restrict__ store32)
{
    constexpr int NT = N / 128;
    const int e = blockIdx.y;
    const int cnt = counts[e];
    const int mt = blockIdx.x / NT, nt = blockIdx.x % NT;
    const int mbase = mt * 64;
    if (mbase >= cnt) return;
    const int nbase = nt * 128;
    const int tid = threadIdx.x;

    __shared__ _Float16 As[64][68];    // stride 68 f16 = 136 B = 34 banks
    __shared__ _Float16 Bs[128][68];   // [n][k]
    __shared__ int rows_s[64];
    __shared__ float pw_s[64];

    if (tid < 64) {
        int idx = mbase + tid; if (idx >= cnt) idx = cnt - 1;
        rows_s[tid] = pair_row[e * CAP + idx];
        pw_s[tid] = UP ? pair_w[e * CAP + idx] : 0.f;
    }
    __syncthreads();

    // A staging: row = tid&63, 16-f16 segment per thread (2 x b128)
    const int arow = tid & 63;
    const int aseg = (tid >> 6) * 16;
    const int pr_a = rows_s[arow];
    const _Float16* asrc = A + (size_t)(UP ? (pr_a >> 1) : pr_a) * K + aseg;

    // B staging: 4 N-rows x 8 K per thread
    const int bn4 = (tid & 31) * 4;
    const int bkb = (tid >> 5) * 8;
    const int* bsrc = qw + ((size_t)e * K + bkb) * N + nbase + bn4;
    const float* ssrc = bsc + ((size_t)e * (K / QGROUP) + (bkb >> 4)) * N + nbase + bn4;

    // prefetch step 0
    uint4 pa0 = *(const uint4*)asrc;
    uint4 pa1 = *(const uint4*)(asrc + 8);
    int4 pc[8];
#pragma unroll
    for (int j = 0; j < 8; j++) pc[j] = *(const int4*)(bsrc + (size_t)j * N);
    float4 psc = *(const float4*)ssrc;

    const int lane = tid & 63, wv = tid >> 6;
    const int quad = lane >> 4, lm = lane & 15;
    const int wm = (wv & 1) * 32, wn = (wv >> 1) * 64;

    float4v acc[2][4];
#pragma unroll
    for (int mi = 0; mi < 2; mi++)
#pragma unroll
        for (int ni = 0; ni < 4; ni++) acc[mi][ni] = (float4v){0.f, 0.f, 0.f, 0.f};

    for (int k0 = 0; k0 < K; k0 += 64) {
        __syncthreads();
        // ---- write prefetched regs -> LDS ----
        *(uint4*)&As[arow][aseg] = pa0;
        *(uint4*)&As[arow][aseg + 8] = pa1;
        {
            half8v h0, h1, h2, h3;
#pragma unroll
            for (int j = 0; j < 8; j++) {
                h0[j] = (_Float16)((float)(pc[j].x - 8) * psc.x);
                h1[j] = (_Float16)((float)(pc[j].y - 8) * psc.y);
                h2[j] = (_Float16)((float)(pc[j].z - 8) * psc.z);
                h3[j] = (_Float16)((float)(pc[j].w - 8) * psc.w);
            }
            *(half8v*)&Bs[bn4 + 0][bkb] = h0;
            *(half8v*)&Bs[bn4 + 1][bkb] = h1;
            *(half8v*)&Bs[bn4 + 2][bkb] = h2;
            *(half8v*)&Bs[bn4 + 3][bkb] = h3;
        }
        __syncthreads();
        // ---- issue next step's loads (overlap with MFMA phase) ----
        if (k0 + 64 < K) {
            asrc += 64;
            pa0 = *(const uint4*)asrc;
            pa1 = *(const uint4*)(asrc + 8);
            bsrc += (size_t)64 * N;
#pragma unroll
            for (int j = 0; j < 8; j++) pc[j] = *(const int4*)(bsrc + (size_t)j * N);
            ssrc += (size_t)4 * N;
            psc = *(const float4*)ssrc;
        }
        // ---- MFMA phase ----
        half8v af[2][2], bf[2][4];
#pragma unroll
        for (int ks = 0; ks < 2; ks++) {
#pragma unroll
            for (int mi = 0; mi < 2; mi++)
                af[ks][mi] = *(const half8v*)&As[wm + mi * 16 + lm][ks * 32 + quad * 8];
#pragma unroll
            for (int ni = 0; ni < 4; ni++)
                bf[ks][ni] = *(const half8v*)&Bs[wn + ni * 16 + lm][ks * 32 + quad * 8];
        }
#pragma unroll
        for (int ks = 0; ks < 2; ks++)
#pragma unroll
            for (int mi = 0; mi < 2; mi++)
#pragma unroll
                for (int ni = 0; ni < 4; ni++)
                    acc[mi][ni] = __builtin_amdgcn_mfma_f32_16x16x32_f16(af[ks][mi], bf[ks][ni], acc[mi][ni], 0, 0, 0);
    }

    const float gs = gsc[0];
#pragma unroll
    for (int mi = 0; mi < 2; mi++) {
#pragma unroll
        for (int r = 0; r < 4; r++) {
            const int rl = wm + mi * 16 + quad * 4 + r;
            if (mbase + rl < cnt) {
                const int pr = rows_s[rl];
#pragma unroll
                for (int ni = 0; ni < 4; ni++) {
                    const int col = nbase + wn + ni * 16 + lm;
                    float v = acc[mi][ni][r] * gs;
                    if (UP) {
                        v = fmaxf(v, 0.f);
                        v = v * v * pw_s[rl];
                        store16[(size_t)pr * N + col] = (_Float16)v;
                    } else if (store16) {
                        store16[(size_t)pr * N + col] = (_Float16)v;
                    } else {
                        atomicAdd(&store32[(size_t)(pr >> 1) * N + col], v);
                    }
                }
            }
        }
    }
}

// ---------------- combine two pair rows -> fp32 out (ydown path) ----------------
__global__ __launch_bounds__(256) void finalize_kernel(
    const _Float16* __restrict__ ydown, float* __restrict__ out)
{
    int i = (blockIdx.x * 256 + threadIdx.x) * 4;   // [TOK*HD)
    int t = i >> 11;
    int h = i & 2047;
    size_t a = ((size_t)t << 12) + h;               // row 2t of [2T][2048]
    half4v ra = *(const half4v*)&ydown[a];
    half4v rb = *(const half4v*)&ydown[a + HD];
    float4 o;
    o.x = (float)ra[0] + (float)rb[0];
    o.y = (float)ra[1] + (float)rb[1];
    o.z = (float)ra[2] + (float)rb[2];
    o.w = (float)ra[3] + (float)rb[3];
    *(float4*)&out[i] = o;
}

extern "C" void kernel_launch(void* const* d_in, const int* in_sizes, int n_in,
                              void* d_out, int out_size, void* d_ws, size_t ws_size,
                              hipStream_t stream) {
    const float* x   = (const float*)d_in[0];
    const float* gw  = (const float*)d_in[1];
    const float* usc = (const float*)d_in[2];
    const float* ugs = (const float*)d_in[3];
    const float* dsc = (const float*)d_in[4];
    const float* dgs = (const float*)d_in[5];
    const int*   uq  = (const int*)d_in[6];
    const int*   dq  = (const int*)d_in[7];
    float* out = (float*)d_out;

    char* ws = (char*)d_ws;
    int*   counts   = (int*)(ws + 0);
    int*   pair_row = (int*)(ws + 4096);
    float* pair_w   = (float*)(ws + 4096 + (size_t)NE * CAP * 4);                 // 266240
    _Float16* xh    = (_Float16*)(ws + 528384);                                   // TOK*HD f16
    _Float16* act   = (_Float16*)(ws + 528384 + (size_t)TOK * HD * 2);            // 2*TOK*ID f16 @17305600
    _Float16* ydown = (_Float16*)(ws + 528384 + (size_t)TOK * HD * 2
                                  + (size_t)2 * TOK * ID * 2);                    // 2*TOK*HD f16 @34082816
    const size_t need_ydown = 34082816ull + (size_t)2 * TOK * HD * 2;             // 67.6 MB
    const bool use_ydown = ws_size >= need_ydown;

    hipMemsetAsync(counts, 0, 4096, stream);
    if (!use_ydown) hipMemsetAsync(out, 0, (size_t)TOK * HD * 4, stream);

    prep_kernel<<<(TOK * HD) / (256 * 8), 256, 0, stream>>>(x, xh);
    router_kernel<<<TOK, 256, 0, stream>>>(x, gw, counts, pair_row, pair_w);
    // up: M=cnt per expert (64-tiles), N=1024, K=2048
    gemm_kernel<ID, HD, true><<<dim3((CAP / 64) * (ID / 128), NE), 256, 0, stream>>>(
        xh, uq, usc, ugs, counts, pair_row, pair_w, act, nullptr);
    // down: N=2048, K=1024
    gemm_kernel<HD, ID, false><<<dim3((CAP / 64) * (HD / 128), NE), 256, 0, stream>>>(
        act, dq, dsc, dgs, counts, pair_row, pair_w,
        use_ydown ? ydown : nullptr, use_ydown ? nullptr : out);
    if (use_ydown)
        finalize_kernel<<<(TOK * HD) / 1024, 256, 0, stream>>>(ydown, out);
}

// Round 6
// 600.114 us; speedup vs baseline: 1.0583x; 1.0583x over previous
//
#include <hip/hip_runtime.h>

#define TOK 4096
#define NE 16
#define HD 2048
#define ID 1024
#define QGROUP 16
#define CAP 4096

typedef _Float16 half4v __attribute__((ext_vector_type(4)));
typedef _Float16 half8v __attribute__((ext_vector_type(8)));
typedef float float4v __attribute__((ext_vector_type(4)));

__device__ __forceinline__ void g2l16(const void* g, void* l) {
    __builtin_amdgcn_global_load_lds(
        (const __attribute__((address_space(1))) unsigned int*)g,
        (__attribute__((address_space(3))) unsigned int*)l, 16, 0, 0);
}

// ---------------- prep: x fp32 -> f16 ----------------
__global__ __launch_bounds__(256) void prep_kernel(
    const float* __restrict__ x, _Float16* __restrict__ xh)
{
    int i8 = (blockIdx.x * 256 + threadIdx.x) * 8;
    float4 f0 = *(const float4*)&x[i8];
    float4 f1 = *(const float4*)&x[i8 + 4];
    half8v h;
    h[0] = (_Float16)f0.x; h[1] = (_Float16)f0.y; h[2] = (_Float16)f0.z; h[3] = (_Float16)f0.w;
    h[4] = (_Float16)f1.x; h[5] = (_Float16)f1.y; h[6] = (_Float16)f1.z; h[7] = (_Float16)f1.w;
    *(half8v*)&xh[i8] = h;
}

// ---------------- router ----------------
__global__ __launch_bounds__(256) void router_kernel(
    const float* __restrict__ x, const float* __restrict__ gw,
    int* __restrict__ counts, int* __restrict__ pair_row, float* __restrict__ pair_w)
{
    int t = blockIdx.x;
    int tid = threadIdx.x;
    float p[NE];
#pragma unroll
    for (int e = 0; e < NE; e++) p[e] = 0.f;
    const float* xr = x + (size_t)t * HD;
    for (int h = tid; h < HD; h += 256) {
        float xv = xr[h];
#pragma unroll
        for (int e = 0; e < NE; e++) p[e] = fmaf(xv, gw[e * HD + h], p[e]);
    }
#pragma unroll
    for (int off = 32; off > 0; off >>= 1) {
#pragma unroll
        for (int e = 0; e < NE; e++) p[e] += __shfl_down(p[e], off, 64);
    }
    __shared__ float part[4][NE];
    int wave = tid >> 6, lane = tid & 63;
    if (lane == 0) {
#pragma unroll
        for (int e = 0; e < NE; e++) part[wave][e] = p[e];
    }
    __syncthreads();
    if (tid == 0) {
        float s[NE]; float sum = 0.f;
#pragma unroll
        for (int e = 0; e < NE; e++) {
            float l = part[0][e] + part[1][e] + part[2][e] + part[3][e];
            float sg = 1.f / (1.f + expf(-l));
            s[e] = sg; sum += sg;
        }
        int i1 = 0;
#pragma unroll
        for (int e = 1; e < NE; e++) if (s[e] > s[i1]) i1 = e;
        int i2 = (i1 == 0) ? 1 : 0;
#pragma unroll
        for (int e = 0; e < NE; e++) if (e != i1 && s[e] > s[i2]) i2 = e;
        float p1 = s[i1] / sum, p2 = s[i2] / sum;
        float inv = 1.f / (p1 + p2 + 1e-20f);
        float w1 = p1 * inv, w2 = p2 * inv;
        int s1 = atomicAdd(&counts[i1], 1);
        pair_row[i1 * CAP + s1] = t * 2;     pair_w[i1 * CAP + s1] = w1;
        int s2 = atomicAdd(&counts[i2], 1);
        pair_row[i2 * CAP + s2] = t * 2 + 1; pair_w[i2 * CAP + s2] = w2;
    }
}

// ---------------- dequant + transpose: codes [E][K][N] int32 -> f16 [E][N][K] ----------------
template<int K, int N>
__global__ __launch_bounds__(256) void dequantT_kernel(
    const int* __restrict__ qw, const float* __restrict__ bsc, _Float16* __restrict__ wq)
{
    const int e = blockIdx.z, kt = blockIdx.y, nt = blockIdx.x;
    const int tid = threadIdx.x;
    __shared__ _Float16 T[64][68];   // [k][n]

    const int c4 = (tid & 15) * 4;
    const int r0 = tid >> 4;         // 0..15
#pragma unroll
    for (int p = 0; p < 4; p++) {
        const int r = p * 16 + r0;
        const int kabs = kt * 64 + r;
        const int4 c = *(const int4*)&qw[((size_t)e * K + kabs) * N + nt * 64 + c4];
        const float4 sc = *(const float4*)&bsc[((size_t)e * (K / QGROUP) + (kabs >> 4)) * N + nt * 64 + c4];
        half4v h;
        h[0] = (_Float16)((float)(c.x - 8) * sc.x);
        h[1] = (_Float16)((float)(c.y - 8) * sc.y);
        h[2] = (_Float16)((float)(c.z - 8) * sc.z);
        h[3] = (_Float16)((float)(c.w - 8) * sc.w);
        *(half4v*)&T[r][c4] = h;
    }
    __syncthreads();
    const int nrow = tid >> 2;
    const int kseg = (tid & 3) * 16;
    half8v o0, o1;
#pragma unroll
    for (int i = 0; i < 8; i++) o0[i] = T[kseg + i][nrow];
#pragma unroll
    for (int i = 0; i < 8; i++) o1[i] = T[kseg + 8 + i][nrow];
    _Float16* dst = wq + ((size_t)e * N + nt * 64 + nrow) * K + kt * 64 + kseg;
    *(half8v*)dst = o0;
    *(half8v*)(dst + 8) = o1;
}

// ---------------- m97-style grouped GEMM on pre-dequantized f16 B^T ----------------
// Tile 128M x 128N x BK=32; 4 waves 2x2; per-wave 4x4 frags of 16x16x32.
template<int N, int K, bool UP>
__global__ __launch_bounds__(256) void gemm2_kernel(
    const _Float16* __restrict__ A, const _Float16* __restrict__ BT,
    const float* __restrict__ gsc,
    const int* __restrict__ counts, const int* __restrict__ pair_row,
    const float* __restrict__ pair_w,
    _Float16* __restrict__ store16, float* __restrict__ store32)
{
    constexpr int NT = N / 128;
    const int e = blockIdx.y;
    const int cnt = counts[e];
    const int mt = blockIdx.x / NT, nt = blockIdx.x % NT;
    const int mbase = mt * 128;
    if (mbase >= cnt) return;
    const int nbase = nt * 128;
    const int tid = threadIdx.x;

    __shared__ _Float16 As[128 * 32];   // [m][k] rows of 64 B, no padding (global_load_lds)
    __shared__ _Float16 Bs[128 * 32];   // [n][k]
    __shared__ int rows_s[128];
    __shared__ float pw_s[128];

    if (tid < 128) {
        int idx = mbase + tid; if (idx >= cnt) idx = cnt - 1;
        rows_s[tid] = pair_row[e * CAP + idx];
        pw_s[tid] = UP ? pair_w[e * CAP + idx] : 0.f;
    }
    __syncthreads();

    const int lane = tid & 63, wv = tid >> 6;
    const int quad = lane >> 4, lm = lane & 15;
    const int wr = (wv >> 1) * 64, wc = (wv & 1) * 64;

    // staging addresses: per wave 2 A-instrs + 2 B-instrs of 1 KB (lane: 16 B)
    const int lsub = lane >> 2;             // 0..15 row within instr
    const int lkof = (lane & 3) * 8;        // f16 offset within 32-k row
    const _Float16* asrc[2];
    const _Float16* bsrc[2];
    _Float16* adst[2];
    _Float16* bdst[2];
#pragma unroll
    for (int i = 0; i < 2; i++) {
        const int lr = wv * 32 + i * 16 + lsub;
        const int pr = rows_s[lr];
        asrc[i] = A + (size_t)(UP ? (pr >> 1) : pr) * K + lkof;
        bsrc[i] = BT + ((size_t)e * N + nbase + lr) * K + lkof;
        adst[i] = &As[(wv * 32 + i * 16) * 32];
        bdst[i] = &Bs[(wv * 32 + i * 16) * 32];
    }

    float4v acc[4][4];
#pragma unroll
    for (int mi = 0; mi < 4; mi++)
#pragma unroll
        for (int ni = 0; ni < 4; ni++) acc[mi][ni] = (float4v){0.f, 0.f, 0.f, 0.f};

    for (int k0 = 0; k0 < K; k0 += 32) {
#pragma unroll
        for (int i = 0; i < 2; i++) {
            g2l16(asrc[i] + k0, adst[i]);
            g2l16(bsrc[i] + k0, bdst[i]);
        }
        __syncthreads();   // drains vmcnt -> LDS ready
        half8v af[4], bf[4];
#pragma unroll
        for (int mi = 0; mi < 4; mi++)
            af[mi] = *(const half8v*)&As[(wr + mi * 16 + lm) * 32 + quad * 8];
#pragma unroll
        for (int ni = 0; ni < 4; ni++)
            bf[ni] = *(const half8v*)&Bs[(wc + ni * 16 + lm) * 32 + quad * 8];
#pragma unroll
        for (int mi = 0; mi < 4; mi++)
#pragma unroll
            for (int ni = 0; ni < 4; ni++)
                acc[mi][ni] = __builtin_amdgcn_mfma_f32_16x16x32_f16(af[mi], bf[ni], acc[mi][ni], 0, 0, 0);
        __syncthreads();   // frags consumed before next overwrite
    }

    const float gs = gsc[0];
#pragma unroll
    for (int mi = 0; mi < 4; mi++) {
#pragma unroll
        for (int r = 0; r < 4; r++) {
            const int rl = wr + mi * 16 + quad * 4 + r;
            if (mbase + rl < cnt) {
                const int pr = rows_s[rl];
#pragma unroll
                for (int ni = 0; ni < 4; ni++) {
                    const int col = nbase + wc + ni * 16 + lm;
                    float v = acc[mi][ni][r] * gs;
                    if (UP) {
                        v = fmaxf(v, 0.f);
                        v = v * v * pw_s[rl];
                        store16[(size_t)pr * N + col] = (_Float16)v;
                    } else {
                        atomicAdd(&store32[(size_t)(pr >> 1) * N + col], v);
                    }
                }
            }
        }
    }
}

// ---------------- fallback fused-dequant GEMM (round-4 structure) ----------------
template<int N, int K, bool UP>
__global__ __launch_bounds__(256) void gemm_fused_kernel(
    const _Float16* __restrict__ A, const int* __restrict__ qw,
    const float* __restrict__ bsc, const float* __restrict__ gsc,
    const int* __restrict__ counts, const int* __restrict__ pair_row,
    const float* __restrict__ pair_w,
    _Float16* __restrict__ store16, float* __restrict__ store32)
{
    constexpr int NT = N / 128;
    const int e = blockIdx.y;
    const int cnt = counts[e];
    const int mt = blockIdx.x / NT, nt = blockIdx.x % NT;
    const int mbase = mt * 128;
    if (mbase >= cnt) return;
    const int nbase = nt * 128;
    const int tid = threadIdx.x;

    __shared__ _Float16 As[128][40];
    __shared__ _Float16 Bs[128][40];
    __shared__ int rows_s[128];
    __shared__ float pw_s[128];

    if (tid < 128) {
        int idx = mbase + tid; if (idx >= cnt) idx = cnt - 1;
        rows_s[tid] = pair_row[e * CAP + idx];
        pw_s[tid] = UP ? pair_w[e * CAP + idx] : 0.f;
    }

    const int lane = tid & 63, wv = tid >> 6;
    const int quad = lane >> 4, lm = lane & 15;
    const int wr = (wv >> 1) * 64, wc = (wv & 1) * 64;

    float4v acc[4][4];
#pragma unroll
    for (int mi = 0; mi < 4; mi++)
#pragma unroll
        for (int ni = 0; ni < 4; ni++) acc[mi][ni] = (float4v){0.f, 0.f, 0.f, 0.f};

    const int am = tid & 127, akk = (tid >> 7) * 16;
    const int bn4 = (tid & 31) * 4, bkb = (tid >> 5) * 4;

    for (int k0 = 0; k0 < K; k0 += 32) {
        __syncthreads();
        {
            int pr = rows_s[am];
            const _Float16* src = A + (size_t)(UP ? (pr >> 1) : pr) * K + k0 + akk;
            *(uint4*)&As[am][akk] = *(const uint4*)src;
            *(uint4*)&As[am][akk + 8] = *(const uint4*)(src + 8);
        }
        {
            const int kabs = k0 + bkb;
            const float4 sc = *(const float4*)&bsc[((size_t)e * (K / QGROUP) + (kabs >> 4)) * N + nbase + bn4];
            const int4 c0 = *(const int4*)&qw[((size_t)e * K + kabs + 0) * N + nbase + bn4];
            const int4 c1 = *(const int4*)&qw[((size_t)e * K + kabs + 1) * N + nbase + bn4];
            const int4 c2 = *(const int4*)&qw[((size_t)e * K + kabs + 2) * N + nbase + bn4];
            const int4 c3 = *(const int4*)&qw[((size_t)e * K + kabs + 3) * N + nbase + bn4];
            half4v q;
            q[0] = (_Float16)((c0.x - 8) * sc.x); q[1] = (_Float16)((c1.x - 8) * sc.x);
            q[2] = (_Float16)((c2.x - 8) * sc.x); q[3] = (_Float16)((c3.x - 8) * sc.x);
            *(half4v*)&Bs[bn4 + 0][bkb] = q;
            q[0] = (_Float16)((c0.y - 8) * sc.y); q[1] = (_Float16)((c1.y - 8) * sc.y);
            q[2] = (_Float16)((c2.y - 8) * sc.y); q[3] = (_Float16)((c3.y - 8) * sc.y);
            *(half4v*)&Bs[bn4 + 1][bkb] = q;
            q[0] = (_Float16)((c0.z - 8) * sc.z); q[1] = (_Float16)((c1.z - 8) * sc.z);
            q[2] = (_Float16)((c2.z - 8) * sc.z); q[3] = (_Float16)((c3.z - 8) * sc.z);
            *(half4v*)&Bs[bn4 + 2][bkb] = q;
            q[0] = (_Float16)((c0.w - 8) * sc.w); q[1] = (_Float16)((c1.w - 8) * sc.w);
            q[2] = (_Float16)((c2.w - 8) * sc.w); q[3] = (_Float16)((c3.w - 8) * sc.w);
            *(half4v*)&Bs[bn4 + 3][bkb] = q;
        }
        __syncthreads();
        half8v af[4], bf[4];
#pragma unroll
        for (int mi = 0; mi < 4; mi++)
            af[mi] = *(const half8v*)&As[wr + mi * 16 + lm][quad * 8];
#pragma unroll
        for (int ni = 0; ni < 4; ni++)
            bf[ni] = *(const half8v*)&Bs[wc + ni * 16 + lm][quad * 8];
#pragma unroll
        for (int mi = 0; mi < 4; mi++)
#pragma unroll
            for (int ni = 0; ni < 4; ni++)
                acc[mi][ni] = __builtin_amdgcn_mfma_f32_16x16x32_f16(af[mi], bf[ni], acc[mi][ni], 0, 0, 0);
    }

    const float gs = gsc[0];
#pragma unroll
    for (int mi = 0; mi < 4; mi++) {
#pragma unroll
        for (int r = 0; r < 4; r++) {
            const int rl = wr + mi * 16 + quad * 4 + r;
            if (mbase + rl < cnt) {
                const int pr = rows_s[rl];
#pragma unroll
                for (int ni = 0; ni < 4; ni++) {
                    const int col = nbase + wc + ni * 16 + lm;
                    float v = acc[mi][ni][r] * gs;
                    if (UP) {
                        v = fmaxf(v, 0.f);
                        v = v * v * pw_s[rl];
                        store16[(size_t)pr * N + col] = (_Float16)v;
                    } else {
                        atomicAdd(&store32[(size_t)(pr >> 1) * N + col], v);
                    }
                }
            }
        }
    }
}

extern "C" void kernel_launch(void* const* d_in, const int* in_sizes, int n_in,
                              void* d_out, int out_size, void* d_ws, size_t ws_size,
                              hipStream_t stream) {
    const float* x   = (const float*)d_in[0];
    const float* gw  = (const float*)d_in[1];
    const float* usc = (const float*)d_in[2];
    const float* ugs = (const float*)d_in[3];
    const float* dsc = (const float*)d_in[4];
    const float* dgs = (const float*)d_in[5];
    const int*   uq  = (const int*)d_in[6];
    const int*   dq  = (const int*)d_in[7];
    float* out = (float*)d_out;

    char* ws = (char*)d_ws;
    int*   counts   = (int*)(ws + 0);
    int*   pair_row = (int*)(ws + 4096);
    float* pair_w   = (float*)(ws + 4096 + (size_t)NE * CAP * 4);        // @266240
    _Float16* xh    = (_Float16*)(ws + 528384);                          // TOK*HD f16 (16.78 MB)
    _Float16* act   = (_Float16*)(ws + 528384 + (size_t)TOK * HD * 2);   // 2*TOK*ID f16 @17.3 MB
    _Float16* wq    = (_Float16*)(ws + 528384 + (size_t)TOK * HD * 2
                                  + (size_t)2 * TOK * ID * 2);           // @34.1 MB, 67.1 MB (reused)
    const size_t need_deq = 34082816ull + (size_t)NE * HD * ID * 2;      // ~101.2 MB
    const bool use_deq = ws_size >= need_deq;

    hipMemsetAsync(counts, 0, 4096, stream);
    hipMemsetAsync(out, 0, (size_t)TOK * HD * 4, stream);   // down-proj accumulates atomically

    prep_kernel<<<(TOK * HD) / (256 * 8), 256, 0, stream>>>(x, xh);
    router_kernel<<<TOK, 256, 0, stream>>>(x, gw, counts, pair_row, pair_w);

    if (use_deq) {
        // up: K=HD=2048, N=ID=1024
        dequantT_kernel<HD, ID><<<dim3(ID / 64, HD / 64, NE), 256, 0, stream>>>(uq, usc, wq);
        gemm2_kernel<ID, HD, true><<<dim3((CAP / 128) * (ID / 128), NE), 256, 0, stream>>>(
            xh, wq, ugs, counts, pair_row, pair_w, act, nullptr);
        // down: K=ID=1024, N=HD=2048 (reuse wq)
        dequantT_kernel<ID, HD><<<dim3(HD / 64, ID / 64, NE), 256, 0, stream>>>(dq, dsc, wq);
        gemm2_kernel<HD, ID, false><<<dim3((CAP / 128) * (HD / 128), NE), 256, 0, stream>>>(
            act, wq, dgs, counts, pair_row, pair_w, nullptr, out);
    } else {
        gemm_fused_kernel<ID, HD, true><<<dim3((CAP / 128) * (ID / 128), NE), 256, 0, stream>>>(
            xh, uq, usc, ugs, counts, pair_row, pair_w, act, nullptr);
        gemm_fused_kernel<HD, ID, false><<<dim3((CAP / 128) * (HD / 128), NE), 256, 0, stream>>>(
            act, dq, dsc, dgs, counts, pair_row, pair_w, nullptr, out);
    }
}

// Round 7
// 541.229 us; speedup vs baseline: 1.1735x; 1.1088x over previous
//
#include <hip/hip_runtime.h>

#define TOK 4096
#define NE 16
#define HD 2048
#define ID 1024
#define QGROUP 16
#define CAP 4096

typedef _Float16 half4v __attribute__((ext_vector_type(4)));
typedef _Float16 half8v __attribute__((ext_vector_type(8)));
typedef float float4v __attribute__((ext_vector_type(4)));

__device__ __forceinline__ void g2l16(const void* g, void* l) {
    __builtin_amdgcn_global_load_lds(
        (const __attribute__((address_space(1))) unsigned int*)g,
        (__attribute__((address_space(3))) unsigned int*)l, 16, 0, 0);
}

// ---------------- prep: x fp32 -> f16 ----------------
__global__ __launch_bounds__(256) void prep_kernel(
    const float* __restrict__ x, _Float16* __restrict__ xh)
{
    int i8 = (blockIdx.x * 256 + threadIdx.x) * 8;
    float4 f0 = *(const float4*)&x[i8];
    float4 f1 = *(const float4*)&x[i8 + 4];
    half8v h;
    h[0] = (_Float16)f0.x; h[1] = (_Float16)f0.y; h[2] = (_Float16)f0.z; h[3] = (_Float16)f0.w;
    h[4] = (_Float16)f1.x; h[5] = (_Float16)f1.y; h[6] = (_Float16)f1.z; h[7] = (_Float16)f1.w;
    *(half8v*)&xh[i8] = h;
}

// ---------------- router: per-token top2, NO atomics ----------------
__global__ __launch_bounds__(256) void router_kernel(
    const float* __restrict__ x, const float* __restrict__ gw,
    int* __restrict__ topi, float* __restrict__ topw)
{
    int t = blockIdx.x;
    int tid = threadIdx.x;
    float p[NE];
#pragma unroll
    for (int e = 0; e < NE; e++) p[e] = 0.f;
    const float* xr = x + (size_t)t * HD;
    for (int h = tid; h < HD; h += 256) {
        float xv = xr[h];
#pragma unroll
        for (int e = 0; e < NE; e++) p[e] = fmaf(xv, gw[e * HD + h], p[e]);
    }
#pragma unroll
    for (int off = 32; off > 0; off >>= 1) {
#pragma unroll
        for (int e = 0; e < NE; e++) p[e] += __shfl_down(p[e], off, 64);
    }
    __shared__ float part[4][NE];
    int wave = tid >> 6, lane = tid & 63;
    if (lane == 0) {
#pragma unroll
        for (int e = 0; e < NE; e++) part[wave][e] = p[e];
    }
    __syncthreads();
    if (tid == 0) {
        float s[NE]; float sum = 0.f;
#pragma unroll
        for (int e = 0; e < NE; e++) {
            float l = part[0][e] + part[1][e] + part[2][e] + part[3][e];
            float sg = 1.f / (1.f + expf(-l));
            s[e] = sg; sum += sg;
        }
        int i1 = 0;
#pragma unroll
        for (int e = 1; e < NE; e++) if (s[e] > s[i1]) i1 = e;
        int i2 = (i1 == 0) ? 1 : 0;
#pragma unroll
        for (int e = 0; e < NE; e++) if (e != i1 && s[e] > s[i2]) i2 = e;
        float p1 = s[i1] / sum, p2 = s[i2] / sum;
        float inv = 1.f / (p1 + p2 + 1e-20f);
        topi[t * 2 + 0] = i1; topw[t * 2 + 0] = p1 * inv;
        topi[t * 2 + 1] = i2; topw[t * 2 + 1] = p2 * inv;
    }
}

// ---------------- compaction: one block per expert, deterministic ordered scan ----------------
__global__ __launch_bounds__(256) void compact_kernel(
    const int* __restrict__ topi, const float* __restrict__ topw,
    int* __restrict__ counts, int* __restrict__ pair_row, float* __restrict__ pair_w)
{
    const int e = blockIdx.x;
    const int tid = threadIdx.x;
    const int lane = tid & 63, wv = tid >> 6;
    __shared__ int wsum[4];
    int running = 0;
    for (int base = 0; base < 2 * TOK; base += 256) {
        const int idx = base + tid;
        const bool f = (topi[idx] == e);
        unsigned long long b = __ballot(f);
        int pre = __popcll(b & ((1ull << lane) - 1ull));
        if (lane == 0) wsum[wv] = __popcll(b);
        __syncthreads();
        int woff = 0;
#pragma unroll
        for (int w = 0; w < 4; w++) if (w < wv) woff += wsum[w];
        const int tot = wsum[0] + wsum[1] + wsum[2] + wsum[3];
        if (f) {
            const int pos = running + woff + pre;
            pair_row[e * CAP + pos] = idx;          // pair id = t*2+slot
            pair_w[e * CAP + pos] = topw[idx];
        }
        running += tot;
        __syncthreads();
    }
    if (tid == 0) counts[e] = running;
}

// ---------------- dequant + transpose: codes [E][K][N] int32 -> f16 [E][N][K] ----------------
template<int K, int N>
__global__ __launch_bounds__(256) void dequantT_kernel(
    const int* __restrict__ qw, const float* __restrict__ bsc, _Float16* __restrict__ wq)
{
    const int e = blockIdx.z, kt = blockIdx.y, nt = blockIdx.x;
    const int tid = threadIdx.x;
    __shared__ _Float16 T[64][68];   // [k][n]

    const int c4 = (tid & 15) * 4;
    const int r0 = tid >> 4;         // 0..15
#pragma unroll
    for (int p = 0; p < 4; p++) {
        const int r = p * 16 + r0;
        const int kabs = kt * 64 + r;
        const int4 c = *(const int4*)&qw[((size_t)e * K + kabs) * N + nt * 64 + c4];
        const float4 sc = *(const float4*)&bsc[((size_t)e * (K / QGROUP) + (kabs >> 4)) * N + nt * 64 + c4];
        half4v h;
        h[0] = (_Float16)((float)(c.x - 8) * sc.x);
        h[1] = (_Float16)((float)(c.y - 8) * sc.y);
        h[2] = (_Float16)((float)(c.z - 8) * sc.z);
        h[3] = (_Float16)((float)(c.w - 8) * sc.w);
        *(half4v*)&T[r][c4] = h;
    }
    __syncthreads();
    const int nrow = tid >> 2;
    const int kseg = (tid & 3) * 16;
    half8v o0, o1;
#pragma unroll
    for (int i = 0; i < 8; i++) o0[i] = T[kseg + i][nrow];
#pragma unroll
    for (int i = 0; i < 8; i++) o1[i] = T[kseg + 8 + i][nrow];
    _Float16* dst = wq + ((size_t)e * N + nt * 64 + nrow) * K + kt * 64 + kseg;
    *(half8v*)dst = o0;
    *(half8v*)(dst + 8) = o1;
}

// ---------------- m97-style grouped GEMM on pre-dequantized f16 B^T ----------------
// Tile 128M x 128N x BK=32; 4 waves 2x2; per-wave 4x4 frags of 16x16x32.
template<int N, int K, bool UP>
__global__ __launch_bounds__(256) void gemm2_kernel(
    const _Float16* __restrict__ A, const _Float16* __restrict__ BT,
    const float* __restrict__ gsc,
    const int* __restrict__ counts, const int* __restrict__ pair_row,
    const float* __restrict__ pair_w,
    _Float16* __restrict__ store16, float* __restrict__ store32)
{
    constexpr int NT = N / 128;
    const int e = blockIdx.y;
    const int cnt = counts[e];
    const int mt = blockIdx.x / NT, nt = blockIdx.x % NT;
    const int mbase = mt * 128;
    if (mbase >= cnt) return;
    const int nbase = nt * 128;
    const int tid = threadIdx.x;

    __shared__ _Float16 As[128 * 32];   // [m][k] rows of 64 B, no padding (global_load_lds)
    __shared__ _Float16 Bs[128 * 32];   // [n][k]
    __shared__ int rows_s[128];
    __shared__ float pw_s[128];

    if (tid < 128) {
        int idx = mbase + tid; if (idx >= cnt) idx = cnt - 1;
        rows_s[tid] = pair_row[e * CAP + idx];
        pw_s[tid] = UP ? pair_w[e * CAP + idx] : 0.f;
    }
    __syncthreads();

    const int lane = tid & 63, wv = tid >> 6;
    const int quad = lane >> 4, lm = lane & 15;
    const int wr = (wv >> 1) * 64, wc = (wv & 1) * 64;

    const int lsub = lane >> 2;             // 0..15 row within instr
    const int lkof = (lane & 3) * 8;        // f16 offset within 32-k row
    const _Float16* asrc[2];
    const _Float16* bsrc[2];
    _Float16* adst[2];
    _Float16* bdst[2];
#pragma unroll
    for (int i = 0; i < 2; i++) {
        const int lr = wv * 32 + i * 16 + lsub;
        const int pr = rows_s[lr];
        asrc[i] = A + (size_t)(UP ? (pr >> 1) : pr) * K + lkof;
        bsrc[i] = BT + ((size_t)e * N + nbase + lr) * K + lkof;
        adst[i] = &As[(wv * 32 + i * 16) * 32];
        bdst[i] = &Bs[(wv * 32 + i * 16) * 32];
    }

    float4v acc[4][4];
#pragma unroll
    for (int mi = 0; mi < 4; mi++)
#pragma unroll
        for (int ni = 0; ni < 4; ni++) acc[mi][ni] = (float4v){0.f, 0.f, 0.f, 0.f};

    for (int k0 = 0; k0 < K; k0 += 32) {
#pragma unroll
        for (int i = 0; i < 2; i++) {
            g2l16(asrc[i] + k0, adst[i]);
            g2l16(bsrc[i] + k0, bdst[i]);
        }
        __syncthreads();   // drains vmcnt -> LDS ready
        half8v af[4], bf[4];
#pragma unroll
        for (int mi = 0; mi < 4; mi++)
            af[mi] = *(const half8v*)&As[(wr + mi * 16 + lm) * 32 + quad * 8];
#pragma unroll
        for (int ni = 0; ni < 4; ni++)
            bf[ni] = *(const half8v*)&Bs[(wc + ni * 16 + lm) * 32 + quad * 8];
#pragma unroll
        for (int mi = 0; mi < 4; mi++)
#pragma unroll
            for (int ni = 0; ni < 4; ni++)
                acc[mi][ni] = __builtin_amdgcn_mfma_f32_16x16x32_f16(af[mi], bf[ni], acc[mi][ni], 0, 0, 0);
        __syncthreads();   // frags consumed before next overwrite
    }

    const float gs = gsc[0];
#pragma unroll
    for (int mi = 0; mi < 4; mi++) {
#pragma unroll
        for (int r = 0; r < 4; r++) {
            const int rl = wr + mi * 16 + quad * 4 + r;
            if (mbase + rl < cnt) {
                const int pr = rows_s[rl];
#pragma unroll
                for (int ni = 0; ni < 4; ni++) {
                    const int col = nbase + wc + ni * 16 + lm;
                    float v = acc[mi][ni][r] * gs;
                    if (UP) {
                        v = fmaxf(v, 0.f);
                        v = v * v * pw_s[rl];
                        store16[(size_t)pr * N + col] = (_Float16)v;
                    } else {
                        atomicAdd(&store32[(size_t)(pr >> 1) * N + col], v);
                    }
                }
            }
        }
    }
}

// ---------------- fallback fused-dequant GEMM (round-4 structure) ----------------
template<int N, int K, bool UP>
__global__ __launch_bounds__(256) void gemm_fused_kernel(
    const _Float16* __restrict__ A, const int* __restrict__ qw,
    const float* __restrict__ bsc, const float* __restrict__ gsc,
    const int* __restrict__ counts, const int* __restrict__ pair_row,
    const float* __restrict__ pair_w,
    _Float16* __restrict__ store16, float* __restrict__ store32)
{
    constexpr int NT = N / 128;
    const int e = blockIdx.y;
    const int cnt = counts[e];
    const int mt = blockIdx.x / NT, nt = blockIdx.x % NT;
    const int mbase = mt * 128;
    if (mbase >= cnt) return;
    const int nbase = nt * 128;
    const int tid = threadIdx.x;

    __shared__ _Float16 As[128][40];
    __shared__ _Float16 Bs[128][40];
    __shared__ int rows_s[128];
    __shared__ float pw_s[128];

    if (tid < 128) {
        int idx = mbase + tid; if (idx >= cnt) idx = cnt - 1;
        rows_s[tid] = pair_row[e * CAP + idx];
        pw_s[tid] = UP ? pair_w[e * CAP + idx] : 0.f;
    }

    const int lane = tid & 63, wv = tid >> 6;
    const int quad = lane >> 4, lm = lane & 15;
    const int wr = (wv >> 1) * 64, wc = (wv & 1) * 64;

    float4v acc[4][4];
#pragma unroll
    for (int mi = 0; mi < 4; mi++)
#pragma unroll
        for (int ni = 0; ni < 4; ni++) acc[mi][ni] = (float4v){0.f, 0.f, 0.f, 0.f};

    const int am = tid & 127, akk = (tid >> 7) * 16;
    const int bn4 = (tid & 31) * 4, bkb = (tid >> 5) * 4;

    for (int k0 = 0; k0 < K; k0 += 32) {
        __syncthreads();
        {
            int pr = rows_s[am];
            const _Float16* src = A + (size_t)(UP ? (pr >> 1) : pr) * K + k0 + akk;
            *(uint4*)&As[am][akk] = *(const uint4*)src;
            *(uint4*)&As[am][akk + 8] = *(const uint4*)(src + 8);
        }
        {
            const int kabs = k0 + bkb;
            const float4 sc = *(const float4*)&bsc[((size_t)e * (K / QGROUP) + (kabs >> 4)) * N + nbase + bn4];
            const int4 c0 = *(const int4*)&qw[((size_t)e * K + kabs + 0) * N + nbase + bn4];
            const int4 c1 = *(const int4*)&qw[((size_t)e * K + kabs + 1) * N + nbase + bn4];
            const int4 c2 = *(const int4*)&qw[((size_t)e * K + kabs + 2) * N + nbase + bn4];
            const int4 c3 = *(const int4*)&qw[((size_t)e * K + kabs + 3) * N + nbase + bn4];
            half4v q;
            q[0] = (_Float16)((c0.x - 8) * sc.x); q[1] = (_Float16)((c1.x - 8) * sc.x);
            q[2] = (_Float16)((c2.x - 8) * sc.x); q[3] = (_Float16)((c3.x - 8) * sc.x);
            *(half4v*)&Bs[bn4 + 0][bkb] = q;
            q[0] = (_Float16)((c0.y - 8) * sc.y); q[1] = (_Float16)((c1.y - 8) * sc.y);
            q[2] = (_Float16)((c2.y - 8) * sc.y); q[3] = (_Float16)((c3.y - 8) * sc.y);
            *(half4v*)&Bs[bn4 + 1][bkb] = q;
            q[0] = (_Float16)((c0.z - 8) * sc.z); q[1] = (_Float16)((c1.z - 8) * sc.z);
            q[2] = (_Float16)((c2.z - 8) * sc.z); q[3] = (_Float16)((c3.z - 8) * sc.z);
            *(half4v*)&Bs[bn4 + 2][bkb] = q;
            q[0] = (_Float16)((c0.w - 8) * sc.w); q[1] = (_Float16)((c1.w - 8) * sc.w);
            q[2] = (_Float16)((c2.w - 8) * sc.w); q[3] = (_Float16)((c3.w - 8) * sc.w);
            *(half4v*)&Bs[bn4 + 3][bkb] = q;
        }
        __syncthreads();
        half8v af[4], bf[4];
#pragma unroll
        for (int mi = 0; mi < 4; mi++)
            af[mi] = *(const half8v*)&As[wr + mi * 16 + lm][quad * 8];
#pragma unroll
        for (int ni = 0; ni < 4; ni++)
            bf[ni] = *(const half8v*)&Bs[wc + ni * 16 + lm][quad * 8];
#pragma unroll
        for (int mi = 0; mi < 4; mi++)
#pragma unroll
            for (int ni = 0; ni < 4; ni++)
                acc[mi][ni] = __builtin_amdgcn_mfma_f32_16x16x32_f16(af[mi], bf[ni], acc[mi][ni], 0, 0, 0);
    }

    const float gs = gsc[0];
#pragma unroll
    for (int mi = 0; mi < 4; mi++) {
#pragma unroll
        for (int r = 0; r < 4; r++) {
            const int rl = wr + mi * 16 + quad * 4 + r;
            if (mbase + rl < cnt) {
                const int pr = rows_s[rl];
#pragma unroll
                for (int ni = 0; ni < 4; ni++) {
                    const int col = nbase + wc + ni * 16 + lm;
                    float v = acc[mi][ni][r] * gs;
                    if (UP) {
                        v = fmaxf(v, 0.f);
                        v = v * v * pw_s[rl];
                        store16[(size_t)pr * N + col] = (_Float16)v;
                    } else {
                        atomicAdd(&store32[(size_t)(pr >> 1) * N + col], v);
                    }
                }
            }
        }
    }
}

extern "C" void kernel_launch(void* const* d_in, const int* in_sizes, int n_in,
                              void* d_out, int out_size, void* d_ws, size_t ws_size,
                              hipStream_t stream) {
    const float* x   = (const float*)d_in[0];
    const float* gw  = (const float*)d_in[1];
    const float* usc = (const float*)d_in[2];
    const float* ugs = (const float*)d_in[3];
    const float* dsc = (const float*)d_in[4];
    const float* dgs = (const float*)d_in[5];
    const int*   uq  = (const int*)d_in[6];
    const int*   dq  = (const int*)d_in[7];
    float* out = (float*)d_out;

    char* ws = (char*)d_ws;
    int*   counts   = (int*)(ws + 0);
    int*   pair_row = (int*)(ws + 4096);
    float* pair_w   = (float*)(ws + 4096 + (size_t)NE * CAP * 4);        // @266240
    _Float16* xh    = (_Float16*)(ws + 528384);                          // TOK*HD f16 (16.78 MB)
    _Float16* act   = (_Float16*)(ws + 528384 + (size_t)TOK * HD * 2);   // 2*TOK*ID f16 @17.3 MB
    _Float16* wq    = (_Float16*)(ws + 528384 + (size_t)TOK * HD * 2
                                  + (size_t)2 * TOK * ID * 2);           // @34.1 MB, 67.1 MB (reused)
    // topi/topw alias the wq region (lifetime: router -> compact, before dequant writes wq)
    int*   topi = (int*)wq;
    float* topw = (float*)((char*)wq + (size_t)2 * TOK * 4);
    const size_t need_deq = 34082816ull + (size_t)NE * HD * ID * 2;      // ~101.2 MB (confirmed fits)
    const bool use_deq = ws_size >= need_deq;

    hipMemsetAsync(out, 0, (size_t)TOK * HD * 4, stream);   // down-proj accumulates atomically

    prep_kernel<<<(TOK * HD) / (256 * 8), 256, 0, stream>>>(x, xh);
    router_kernel<<<TOK, 256, 0, stream>>>(x, gw, topi, topw);
    compact_kernel<<<NE, 256, 0, stream>>>(topi, topw, counts, pair_row, pair_w);

    if (use_deq) {
        // up: K=HD=2048, N=ID=1024
        dequantT_kernel<HD, ID><<<dim3(ID / 64, HD / 64, NE), 256, 0, stream>>>(uq, usc, wq);
        gemm2_kernel<ID, HD, true><<<dim3((CAP / 128) * (ID / 128), NE), 256, 0, stream>>>(
            xh, wq, ugs, counts, pair_row, pair_w, act, nullptr);
        // down: K=ID=1024, N=HD=2048 (reuse wq)
        dequantT_kernel<ID, HD><<<dim3(HD / 64, ID / 64, NE), 256, 0, stream>>>(dq, dsc, wq);
        gemm2_kernel<HD, ID, false><<<dim3((CAP / 128) * (HD / 128), NE), 256, 0, stream>>>(
            act, wq, dgs, counts, pair_row, pair_w, nullptr, out);
    } else {
        gemm_fused_kernel<ID, HD, true><<<dim3((CAP / 128) * (ID / 128), NE), 256, 0, stream>>>(
            xh, uq, usc, ugs, counts, pair_row, pair_w, act, nullptr);
        gemm_fused_kernel<HD, ID, false><<<dim3((CAP / 128) * (HD / 128), NE), 256, 0, stream>>>(
            act, dq, dsc, dgs, counts, pair_row, pair_w, nullptr, out);
    }
}